// Round 6
// baseline (296.079 us; speedup 1.0000x reference)
//
#include <hip/hip_runtime.h>
#include <hip/hip_bf16.h>

#define V_SIZE 32000
#define SEQ 64
#define BATCH 64
#define EMB 32
#define HID 16
#define NROWS (SEQ * BATCH)   // 4096
#define V4 (V_SIZE / 4)       // 8000 float4 columns
#define STRIPS 32             // 32 strips * 256 f4-cols = 8192 >= 8000
#define CHUNKS 32
#define ROWS_W (NROWS / CHUNKS)   // 128 rows per chunk
#define NSLOTS (STRIPS * 4)       // per-wave partial slots per row

typedef float f32x4 __attribute__((ext_vector_type(4)));

// ---------------------------------------------------------------------------
// Kernel A: h_table[r][j] = sigmoid( lookup[idx[r]] . wx[:,j] + (h0 @ wh)[j] )
// ---------------------------------------------------------------------------
__global__ __launch_bounds__(256) void k_htable(
    const int* __restrict__ idx, const float* __restrict__ lookup,
    const float* __restrict__ wx, const float* __restrict__ wh,
    const float* __restrict__ h0, float* __restrict__ h_table)
{
    int r = blockIdx.x * 256 + threadIdx.x;
    if (r >= NROWS) return;

    float acc[HID];
    #pragma unroll
    for (int j = 0; j < HID; ++j) acc[j] = 0.f;

    #pragma unroll
    for (int i = 0; i < HID; ++i) {
        float h0i = h0[i];
        #pragma unroll
        for (int j = 0; j < HID; ++j) acc[j] += h0i * wh[i * HID + j];
    }

    int tok = idx[r];
    const float* xrow = lookup + (long)tok * EMB;
    #pragma unroll
    for (int e = 0; e < EMB; ++e) {
        float x = xrow[e];
        #pragma unroll
        for (int j = 0; j < HID; ++j) acc[j] += x * wx[e * HID + j];
    }

    #pragma unroll
    for (int j = 0; j < HID; ++j)
        h_table[r * HID + j] = 1.f / (1.f + __expf(-acc[j]));
}

// ---------------------------------------------------------------------------
// Kernel B (flipped): per-wave partial exp-sums.
// Thread owns ONE float4 column; its 16 Wo float4s live in registers for all
// 128 rows of its chunk. Per row: dot -> 4 exps -> wave butterfly ->
// lane0 stores partial[strip*4+wave][r]. Deterministic (fixed slot order).
// Wo L2 traffic: 1024 blocks * 64 KB = 64 MB.
// ---------------------------------------------------------------------------
__global__ __launch_bounds__(256) void k_expsum(
    const float* __restrict__ h_table, const float* __restrict__ wo,
    float* __restrict__ partial)
{
    const int tid = threadIdx.x;
    const int strip = blockIdx.x & (STRIPS - 1);
    const int chunk = blockIdx.x / STRIPS;
    const int v4 = strip * 256 + tid;
    const bool act = v4 < V4;
    const int r0 = chunk * ROWS_W;
    const int wave = tid >> 6;
    const int lane = tid & 63;

    const f32x4* wo4 = reinterpret_cast<const f32x4*>(wo);
    f32x4 w[HID];
    #pragma unroll
    for (int j = 0; j < HID; ++j) {
        if (act) w[j] = wo4[j * V4 + v4];
        else     w[j] = (f32x4){0.f, 0.f, 0.f, 0.f};
    }

    float* slot = partial + (size_t)(strip * 4 + wave) * NROWS;

    for (int r = r0; r < r0 + ROWS_W; ++r) {
        const float* h = h_table + r * HID;   // wave-uniform -> s_load
        float l0 = 0.f, l1 = 0.f, l2 = 0.f, l3 = 0.f;
        #pragma unroll
        for (int j = 0; j < HID; ++j) {
            float hj = h[j];
            l0 += hj * w[j].x;
            l1 += hj * w[j].y;
            l2 += hj * w[j].z;
            l3 += hj * w[j].w;
        }
        float s = act ? (__expf(l0) + __expf(l1) + __expf(l2) + __expf(l3)) : 0.f;
        #pragma unroll
        for (int off = 32; off >= 1; off >>= 1)
            s += __shfl_xor(s, off, 64);
        if (lane == 0) slot[r] = s;
    }
}

// ---------------------------------------------------------------------------
// Kernel B2: lse[r] = log( sum over 128 slots of partial[slot][r] )
// Fixed summation order -> deterministic. 2 MB of reads, trivial.
// ---------------------------------------------------------------------------
__global__ __launch_bounds__(256) void k_reduce(
    const float* __restrict__ partial, float* __restrict__ lse)
{
    int r = blockIdx.x * 256 + threadIdx.x;
    if (r >= NROWS) return;
    float s = 0.f;
    #pragma unroll
    for (int k = 0; k < NSLOTS; ++k)
        s += partial[(size_t)k * NROWS + r];
    lse[r] = __logf(s);
}

// ---------------------------------------------------------------------------
// Kernel C: thread owns ONE float4 column; Wo in registers across 128 rows.
// Regular (cached) stores — the fill kernels prove these stream at ~6.9 TB/s,
// and Wo is only read at block start so L2 thrash by the store stream is
// harmless.
// ---------------------------------------------------------------------------
__global__ __launch_bounds__(256) void k_write(
    const float* __restrict__ h_table, const float* __restrict__ wo,
    const float* __restrict__ lse, float* __restrict__ out)
{
    const int tid = threadIdx.x;
    const int strip = blockIdx.x & (STRIPS - 1);
    const int chunk = blockIdx.x / STRIPS;
    const int v4 = strip * 256 + tid;
    const bool act = v4 < V4;
    const int r0 = chunk * ROWS_W;

    const f32x4* wo4 = reinterpret_cast<const f32x4*>(wo);
    f32x4 w[HID];
    #pragma unroll
    for (int j = 0; j < HID; ++j) {
        if (act) w[j] = wo4[j * V4 + v4];
        else     w[j] = (f32x4){0.f, 0.f, 0.f, 0.f};
    }

    f32x4* out4 = reinterpret_cast<f32x4*>(out);

    for (int r = r0; r < r0 + ROWS_W; ++r) {
        const float* h = h_table + r * HID;   // wave-uniform -> s_load
        const float ls = lse[r];              // wave-uniform -> s_load

        float l0 = 0.f, l1 = 0.f, l2 = 0.f, l3 = 0.f;
        #pragma unroll
        for (int j = 0; j < HID; ++j) {
            float hj = h[j];
            l0 += hj * w[j].x;
            l1 += hj * w[j].y;
            l2 += hj * w[j].z;
            l3 += hj * w[j].w;
        }
        if (act) {
            f32x4 o;
            o.x = l0 - ls; o.y = l1 - ls; o.z = l2 - ls; o.w = l3 - ls;
            out4[(long)r * V4 + v4] = o;
        }
    }
}

extern "C" void kernel_launch(void* const* d_in, const int* in_sizes, int n_in,
                              void* d_out, int out_size, void* d_ws, size_t ws_size,
                              hipStream_t stream) {
    const int*   idx    = (const int*)d_in[0];
    const float* lookup = (const float*)d_in[1];
    const float* wx     = (const float*)d_in[2];
    const float* wh     = (const float*)d_in[3];
    const float* wo     = (const float*)d_in[4];
    const float* h0     = (const float*)d_in[5];
    float* out = (float*)d_out;

    float* h_table = (float*)d_ws;                    // 4096*16 floats (256 KB)
    float* lse     = h_table + NROWS * HID;           // 4096 floats
    float* partial = lse + NROWS;                     // 128*4096 floats (2 MB)

    k_htable<<<NROWS / 256, 256, 0, stream>>>(idx, lookup, wx, wh, h0, h_table);
    k_expsum<<<STRIPS * CHUNKS, 256, 0, stream>>>(h_table, wo, partial);
    k_reduce<<<NROWS / 256, 256, 0, stream>>>(partial, lse);
    k_write<<<STRIPS * CHUNKS, 256, 0, stream>>>(h_table, wo, lse, out);
}

// Round 7
// 236.035 us; speedup vs baseline: 1.2544x; 1.2544x over previous
//
#include <hip/hip_runtime.h>
#include <hip/hip_bf16.h>

#define V_SIZE 32000
#define SEQ 64
#define BATCH 64
#define EMB 32
#define HID 16
#define NROWS (SEQ * BATCH)   // 4096
#define V4 (V_SIZE / 4)       // 8000 float4 columns
#define STRIPS 32             // 32 strips * 256 f4-cols = 8192 >= 8000
#define CHUNKS 64
#define ROWS_W (NROWS / CHUNKS)   // 64 rows per chunk
#define NSLOTS (STRIPS * 4)       // per-wave partial slots per row

typedef float f32x4 __attribute__((ext_vector_type(4)));

// ---------------------------------------------------------------------------
// Kernel A: h_table[r][j] = sigmoid( lookup[idx[r]] . wx[:,j] + (h0 @ wh)[j] )
// ---------------------------------------------------------------------------
__global__ __launch_bounds__(256) void k_htable(
    const int* __restrict__ idx, const float* __restrict__ lookup,
    const float* __restrict__ wx, const float* __restrict__ wh,
    const float* __restrict__ h0, float* __restrict__ h_table)
{
    int r = blockIdx.x * 256 + threadIdx.x;
    if (r >= NROWS) return;

    float acc[HID];
    #pragma unroll
    for (int j = 0; j < HID; ++j) acc[j] = 0.f;

    #pragma unroll
    for (int i = 0; i < HID; ++i) {
        float h0i = h0[i];
        #pragma unroll
        for (int j = 0; j < HID; ++j) acc[j] += h0i * wh[i * HID + j];
    }

    int tok = idx[r];
    const float* xrow = lookup + (long)tok * EMB;
    #pragma unroll
    for (int e = 0; e < EMB; ++e) {
        float x = xrow[e];
        #pragma unroll
        for (int j = 0; j < HID; ++j) acc[j] += x * wx[e * HID + j];
    }

    #pragma unroll
    for (int j = 0; j < HID; ++j)
        h_table[r * HID + j] = 1.f / (1.f + __expf(-acc[j]));
}

// ---------------------------------------------------------------------------
// Kernel B: per-wave partial exp-sums, 4-row groups for ILP.
// Thread owns ONE float4 column; 16 Wo float4s in registers for its chunk.
// Per 4-row group: 4 independent dot chains -> 16 exps -> 4 interleaved
// butterflies -> lane0 stores f32x4 of partials. Deterministic slot order.
// ---------------------------------------------------------------------------
__global__ __launch_bounds__(256) void k_expsum(
    const float* __restrict__ h_table, const float* __restrict__ wo,
    float* __restrict__ partial)
{
    const int tid = threadIdx.x;
    const int strip = blockIdx.x & (STRIPS - 1);
    const int chunk = blockIdx.x / STRIPS;
    const int v4 = strip * 256 + tid;
    const bool act = v4 < V4;
    const int r0 = chunk * ROWS_W;
    const int wave = tid >> 6;
    const int lane = tid & 63;

    const f32x4* wo4 = reinterpret_cast<const f32x4*>(wo);
    f32x4 w[HID];
    #pragma unroll
    for (int j = 0; j < HID; ++j) {
        if (act) w[j] = wo4[j * V4 + v4];
        else     w[j] = (f32x4){0.f, 0.f, 0.f, 0.f};
    }

    float* slot = partial + (size_t)(strip * 4 + wave) * NROWS;

    for (int rr = r0; rr < r0 + ROWS_W; rr += 4) {
        f32x4 acc[4];
        #pragma unroll
        for (int i = 0; i < 4; ++i) acc[i] = (f32x4){0.f, 0.f, 0.f, 0.f};

        #pragma unroll
        for (int q = 0; q < 4; ++q) {
            f32x4 h4[4];
            #pragma unroll
            for (int i = 0; i < 4; ++i)
                h4[i] = *reinterpret_cast<const f32x4*>(h_table + (rr + i) * HID + q * 4);
            #pragma unroll
            for (int i = 0; i < 4; ++i) {
                acc[i] += h4[i].x * w[q * 4 + 0];
                acc[i] += h4[i].y * w[q * 4 + 1];
                acc[i] += h4[i].z * w[q * 4 + 2];
                acc[i] += h4[i].w * w[q * 4 + 3];
            }
        }

        float s[4];
        #pragma unroll
        for (int i = 0; i < 4; ++i) {
            float e = __expf(acc[i].x) + __expf(acc[i].y) +
                      __expf(acc[i].z) + __expf(acc[i].w);
            s[i] = act ? e : 0.f;
        }

        // 4 interleaved butterflies (independent chains pipeline in DS)
        #pragma unroll
        for (int off = 32; off >= 1; off >>= 1) {
            #pragma unroll
            for (int i = 0; i < 4; ++i)
                s[i] += __shfl_xor(s[i], off, 64);
        }

        if (lane == 0) {
            f32x4 o = {s[0], s[1], s[2], s[3]};
            *reinterpret_cast<f32x4*>(slot + rr) = o;
        }
    }
}

// ---------------------------------------------------------------------------
// Kernel B2: lse[r] = log( sum over 128 slots of partial[slot][r] )
// Fixed summation order -> deterministic.
// ---------------------------------------------------------------------------
__global__ __launch_bounds__(256) void k_reduce(
    const float* __restrict__ partial, float* __restrict__ lse)
{
    int r = blockIdx.x * 256 + threadIdx.x;
    if (r >= NROWS) return;
    float s = 0.f;
    #pragma unroll
    for (int k = 0; k < NSLOTS; ++k)
        s += partial[(size_t)k * NROWS + r];
    lse[r] = __logf(s);
}

// ---------------------------------------------------------------------------
// Kernel C: thread owns ONE float4 column; Wo in registers; 4-row groups
// for ILP (4 independent dot chains + 4 batched stores per group).
// ---------------------------------------------------------------------------
__global__ __launch_bounds__(256) void k_write(
    const float* __restrict__ h_table, const float* __restrict__ wo,
    const float* __restrict__ lse, float* __restrict__ out)
{
    const int tid = threadIdx.x;
    const int strip = blockIdx.x & (STRIPS - 1);
    const int chunk = blockIdx.x / STRIPS;
    const int v4 = strip * 256 + tid;
    const bool act = v4 < V4;
    const int r0 = chunk * ROWS_W;

    const f32x4* wo4 = reinterpret_cast<const f32x4*>(wo);
    f32x4 w[HID];
    #pragma unroll
    for (int j = 0; j < HID; ++j) {
        if (act) w[j] = wo4[j * V4 + v4];
        else     w[j] = (f32x4){0.f, 0.f, 0.f, 0.f};
    }

    f32x4* out4 = reinterpret_cast<f32x4*>(out);

    for (int rr = r0; rr < r0 + ROWS_W; rr += 4) {
        f32x4 acc[4];
        #pragma unroll
        for (int i = 0; i < 4; ++i) acc[i] = (f32x4){0.f, 0.f, 0.f, 0.f};

        #pragma unroll
        for (int q = 0; q < 4; ++q) {
            f32x4 h4[4];
            #pragma unroll
            for (int i = 0; i < 4; ++i)
                h4[i] = *reinterpret_cast<const f32x4*>(h_table + (rr + i) * HID + q * 4);
            #pragma unroll
            for (int i = 0; i < 4; ++i) {
                acc[i] += h4[i].x * w[q * 4 + 0];
                acc[i] += h4[i].y * w[q * 4 + 1];
                acc[i] += h4[i].z * w[q * 4 + 2];
                acc[i] += h4[i].w * w[q * 4 + 3];
            }
        }

        const f32x4 lsv = *reinterpret_cast<const f32x4*>(lse + rr);

        if (act) {
            #pragma unroll
            for (int i = 0; i < 4; ++i) {
                f32x4 o = acc[i] - lsv[i];
                out4[(long)(rr + i) * V4 + v4] = o;
            }
        }
    }
}

extern "C" void kernel_launch(void* const* d_in, const int* in_sizes, int n_in,
                              void* d_out, int out_size, void* d_ws, size_t ws_size,
                              hipStream_t stream) {
    const int*   idx    = (const int*)d_in[0];
    const float* lookup = (const float*)d_in[1];
    const float* wx     = (const float*)d_in[2];
    const float* wh     = (const float*)d_in[3];
    const float* wo     = (const float*)d_in[4];
    const float* h0     = (const float*)d_in[5];
    float* out = (float*)d_out;

    float* h_table = (float*)d_ws;                    // 4096*16 floats (256 KB)
    float* lse     = h_table + NROWS * HID;           // 4096 floats
    float* partial = lse + NROWS;                     // 128*4096 floats (2 MB)

    k_htable<<<NROWS / 256, 256, 0, stream>>>(idx, lookup, wx, wh, h0, h_table);
    k_expsum<<<STRIPS * CHUNKS, 256, 0, stream>>>(h_table, wo, partial);
    k_reduce<<<NROWS / 256, 256, 0, stream>>>(partial, lse);
    k_write<<<STRIPS * CHUNKS, 256, 0, stream>>>(h_table, wo, lse, out);
}